// Round 18
// baseline (796.616 us; speedup 1.0000x reference)
//
#include <hip/hip_runtime.h>
#include <math.h>

#define B_ROWS 8192
#define P_KEYS 2048
#define D_DIM  768
#define L_LEN  5
#define K_SEL  5
#define EPSV   1e-8f

#define RBLK   64                  // rows per block (4 waves x 16)
#define CBLK   64                  // cols per block
#define NCB2   (P_KEYS / CBLK)     // 32 col blocks
#define KC     32                  // MFMA K per stage
#define NKC    (D_DIM / KC)        // 24
#define NCAND  (NCB2 * K_SEL)      // 160 candidates per row
#define NRESC  16                  // exact-rescored candidates per row

typedef _Float16 half8  __attribute__((ext_vector_type(8)));
typedef _Float16 half4v __attribute__((ext_vector_type(4)));
typedef float    f32x4  __attribute__((ext_vector_type(4)));

// sorted ascending (v[0] best). Tie-break: lower index wins (jax top_k semantics).
__device__ inline void insert5(float (&v)[K_SEL], int (&ix)[K_SEL], float nv, int ni) {
    if (nv < v[K_SEL-1] || (nv == v[K_SEL-1] && ni < ix[K_SEL-1])) {
        v[K_SEL-1] = nv; ix[K_SEL-1] = ni;
        #pragma unroll
        for (int j = K_SEL-1; j > 0; --j) {
            bool sw = (v[j] < v[j-1]) || (v[j] == v[j-1] && ix[j] < ix[j-1]);
            if (sw) {
                float tv = v[j]; v[j] = v[j-1]; v[j-1] = tv;
                int   ti = ix[j]; ix[j] = ix[j-1]; ix[j-1] = ti;
            }
        }
    }
}

// One wave per row. Keys: -> kn (fp32 normalized, exact-rescore input) and
// kh (fp16). X rows: -> inv_x AND xh = fp16(x * inv_x), precomputed once.
__global__ __launch_bounds__(256)
void norm_kernel(const float* __restrict__ x, const float* __restrict__ pk,
                 float* __restrict__ kn, _Float16* __restrict__ kh,
                 _Float16* __restrict__ xh, float* __restrict__ inv_x) {
    int wave = (blockIdx.x * blockDim.x + threadIdx.x) >> 6;
    int lane = threadIdx.x & 63;
    bool is_key = (wave < P_KEYS);
    int row = is_key ? wave : wave - P_KEYS;
    const float* src = is_key ? (pk + (size_t)row * D_DIM) : (x + (size_t)row * D_DIM);

    const float4* s4 = (const float4*)src;
    float4 v[3];
    float s = 0.f;
    #pragma unroll
    for (int i = 0; i < 3; ++i) {
        v[i] = s4[lane + 64 * i];
        s += v[i].x * v[i].x + v[i].y * v[i].y + v[i].z * v[i].z + v[i].w * v[i].w;
    }
    #pragma unroll
    for (int off = 32; off; off >>= 1) s += __shfl_xor(s, off, 64);
    float inv = 1.0f / fmaxf(sqrtf(s), EPSV);

    if (is_key) {
        float4* d4 = (float4*)(kn + (size_t)row * D_DIM);
        #pragma unroll
        for (int i = 0; i < 3; ++i) {
            float4 w = v[i];
            w.x *= inv; w.y *= inv; w.z *= inv; w.w *= inv;
            d4[lane + 64 * i] = w;
            half4v h = { (_Float16)w.x, (_Float16)w.y, (_Float16)w.z, (_Float16)w.w };
            *(half4v*)(kh + (size_t)row * D_DIM + (lane + 64 * i) * 4) = h;
        }
    } else {
        #pragma unroll
        for (int i = 0; i < 3; ++i) {
            float4 w = v[i];
            half4v h = { (_Float16)(w.x * inv), (_Float16)(w.y * inv),
                         (_Float16)(w.z * inv), (_Float16)(w.w * inv) };
            *(half4v*)(xh + (size_t)row * D_DIM + (lane + 64 * i) * 4) = h;
        }
        if (lane == 0) inv_x[row] = inv;
    }
}

// Approx pass v4: BARRIER-FREE fp16 MFMA, fragments loaded DIRECTLY from L2.
// r14/r15/r17 post-mortem: three different kernels all sat at ~435 us with
// MfmaUtil<=2.4% / VALU<=47% — the shared LDS-stage + 2x full-drain-barrier
// per k-chunk structure was the limiter (vmcnt(0) drains on the critical path
// 24x per block), not the math. kh (3MB) and the shared xh row slab (192KB per
// 32-block group) are L2-resident -> LDS staging is pure overhead (Common-
// mistake #7). Now each lane global-loads its fragment (one dwordx4 per wave
// covers exactly 16x64B lines, zero waste): 5 loads + 4 MFMAs per chunk, zero
// barriers, zero LDS. MFMA sequence identical to r17 -> approx values bitwise
// unchanged. #pragma unroll 2 bounds in-flight regs (VGPR ~70, safe zone).
__global__ __launch_bounds__(256)
void approx_kernel(const _Float16* __restrict__ xh, const _Float16* __restrict__ kh,
                   float* __restrict__ cand_val, unsigned short* __restrict__ cand_idx) {
    const int cb = blockIdx.x, rb = blockIdx.y;
    const int col0 = cb * CBLK, row0 = rb * RBLK;
    const int tid = threadIdx.x, lane = tid & 63, w = tid >> 6;

    const int mrow = lane & 15;            // m (A) / n (B) within a 16-frag
    const int fk   = lane >> 4;            // k-group

    const _Float16* ap  = xh + (size_t)(row0 + w * 16 + mrow) * D_DIM + fk * 8;
    const _Float16* bp0 = kh + (size_t)(col0 +  0 + mrow) * D_DIM + fk * 8;
    const _Float16* bp1 = kh + (size_t)(col0 + 16 + mrow) * D_DIM + fk * 8;
    const _Float16* bp2 = kh + (size_t)(col0 + 32 + mrow) * D_DIM + fk * 8;
    const _Float16* bp3 = kh + (size_t)(col0 + 48 + mrow) * D_DIM + fk * 8;

    f32x4 acc[4];
    #pragma unroll
    for (int fj = 0; fj < 4; ++fj) acc[fj] = (f32x4){0.f, 0.f, 0.f, 0.f};

    #pragma unroll 2
    for (int kc = 0; kc < NKC; ++kc) {
        const int k0 = kc * KC;
        half8 a  = *(const half8*)(ap  + k0);
        half8 b0 = *(const half8*)(bp0 + k0);
        half8 b1 = *(const half8*)(bp1 + k0);
        half8 b2 = *(const half8*)(bp2 + k0);
        half8 b3 = *(const half8*)(bp3 + k0);
        acc[0] = __builtin_amdgcn_mfma_f32_16x16x32_f16(a, b0, acc[0], 0, 0, 0);
        acc[1] = __builtin_amdgcn_mfma_f32_16x16x32_f16(a, b1, acc[1], 0, 0, 0);
        acc[2] = __builtin_amdgcn_mfma_f32_16x16x32_f16(a, b2, acc[2], 0, 0, 0);
        acc[3] = __builtin_amdgcn_mfma_f32_16x16x32_f16(a, b3, acc[3], 0, 0, 0);
    }

    // epilogue (r17-verified): lane holds D[m=(lane>>4)*4+r][n=lane&15] per fj
    #pragma unroll
    for (int r = 0; r < 4; ++r) {
        float tv[K_SEL]; int tix[K_SEL];
        #pragma unroll
        for (int j = 0; j < K_SEL; ++j) { tv[j] = 3.0e38f; tix[j] = 0x7fffffff; }
        #pragma unroll
        for (int fj = 0; fj < 4; ++fj)
            insert5(tv, tix, 1.0f - acc[fj][r], col0 + fj * 16 + mrow);
        #pragma unroll
        for (int off = 1; off < 16; off <<= 1) {
            float ov[K_SEL]; int oi[K_SEL];
            #pragma unroll
            for (int j = 0; j < K_SEL; ++j) {
                ov[j] = __shfl_xor(tv[j], off, 16);
                oi[j] = __shfl_xor(tix[j], off, 16);
            }
            #pragma unroll
            for (int j = 0; j < K_SEL; ++j) insert5(tv, tix, ov[j], oi[j]);
        }
        if (mrow == 0) {
            int grow = row0 + w * 16 + fk * 4 + r;
            #pragma unroll
            for (int j = 0; j < K_SEL; ++j) {
                cand_val[(size_t)grow * NCAND + cb * K_SEL + j] = tv[j];
                cand_idx[(size_t)grow * NCAND + cb * K_SEL + j] = (unsigned short)tix[j];
            }
        }
    }
}

// select_rescore v2: ONE WAVE PER ROW (the r17 version's rank loop did 512
// broadcast LDS reads per thread ~ >100 us hidden). Candidates packed as u64
// keys ((bits(val+4.0f)<<32)|idx — positive floats order as uints; the +4.0
// bias only perturbs candidate-set membership among statistical ties, which
// the exact rescore absorbs). 16x shfl-min-extract, then 16 lanes rescore in
// parallel with the EXACT sequential fp32 dot of the passing rounds.
__global__ __launch_bounds__(256)
void select_rescore_kernel(const float* __restrict__ x, const float* __restrict__ kn,
                           const float* __restrict__ inv_x,
                           const float* __restrict__ cand_val,
                           const unsigned short* __restrict__ cand_idx,
                           float* __restrict__ out_dist, int* __restrict__ final_idx) {
    const int lane = threadIdx.x & 63;
    const int row  = blockIdx.x * 4 + (threadIdx.x >> 6);
    const size_t base = (size_t)row * NCAND;

    // load 160 candidates into 3 per-lane key slots (slot2 valid for lane<32)
    unsigned long long k0, k1, k2 = ~0ull;
    {
        float v0 = cand_val[base + lane];
        unsigned i0 = cand_idx[base + lane];
        k0 = ((unsigned long long)__float_as_uint(v0 + 4.0f) << 32) | i0;
        float v1 = cand_val[base + 64 + lane];
        unsigned i1 = cand_idx[base + 64 + lane];
        k1 = ((unsigned long long)__float_as_uint(v1 + 4.0f) << 32) | i1;
        if (lane < 32) {
            float v2 = cand_val[base + 128 + lane];
            unsigned i2 = cand_idx[base + 128 + lane];
            k2 = ((unsigned long long)__float_as_uint(v2 + 4.0f) << 32) | i2;
        }
    }

    // 16x min-extract (keys unique: idx distinct across disjoint col blocks)
    unsigned long long mykey = ~0ull;
    #pragma unroll
    for (int it = 0; it < NRESC; ++it) {
        unsigned long long m = (k0 < k1) ? k0 : k1;
        m = (k2 < m) ? k2 : m;
        #pragma unroll
        for (int off = 32; off; off >>= 1) {
            unsigned long long o = __shfl_xor(m, off, 64);
            m = (o < m) ? o : m;
        }
        if (lane == it) mykey = m;      // static lane==it: no runtime indexing
        if (k0 == m) k0 = ~0ull;
        if (k1 == m) k1 = ~0ull;
        if (k2 == m) k2 = ~0ull;
    }

    // lanes 0..15: exact rescore (sequential fp32, identical to passing rounds)
    float ds = 3.0e38f; int ci = 0x7fffffff;
    if (lane < NRESC) {
        ci = (int)(unsigned)(mykey & 0xFFFFFFFFull);
        float invx = inv_x[row];
        const float4* xp = (const float4*)(x + (size_t)row * D_DIM);
        const float4* bp = (const float4*)(kn + (size_t)ci * D_DIM);
        float s = 0.f;
        for (int k = 0; k < D_DIM / 4; ++k) {
            float4 xv = xp[k], bv = bp[k];
            s += (xv.x * invx) * bv.x;
            s += (xv.y * invx) * bv.y;
            s += (xv.z * invx) * bv.z;
            s += (xv.w * invx) * bv.w;
        }
        ds = 1.0f - s;
    }

    // lane 0: final top-5 by (exact value, index)
    float fv[K_SEL]; int fi[K_SEL];
    #pragma unroll
    for (int j = 0; j < K_SEL; ++j) { fv[j] = 3.0e38f; fi[j] = 0x7fffffff; }
    #pragma unroll
    for (int j = 0; j < NRESC; ++j) {
        float v = __shfl(ds, j, 64);
        int   i = __shfl(ci, j, 64);
        insert5(fv, fi, v, i);
    }
    if (lane == 0) {
        #pragma unroll
        for (int j = 0; j < K_SEL; ++j) {
            out_dist[(size_t)row * K_SEL + j] = fv[j];
            final_idx[(size_t)row * K_SEL + j] = fi[j];
        }
    }
}

// one block per (b, s): copy prompts[idx] (5*768 floats = 960 float4) to output
__global__ __launch_bounds__(256)
void gather_kernel(const float* __restrict__ prompts, const int* __restrict__ final_idx,
                   float* __restrict__ out1) {
    int bs = blockIdx.x;                 // 0 .. B_ROWS*K_SEL-1
    int p = final_idx[bs];
    const float4* src = (const float4*)(prompts + (size_t)p * (L_LEN * D_DIM));
    float4* dst = (float4*)(out1 + (size_t)bs * (L_LEN * D_DIM));
    const int n4 = (L_LEN * D_DIM) / 4;  // 960
    for (int i = threadIdx.x; i < n4; i += blockDim.x) dst[i] = src[i];
}

extern "C" void kernel_launch(void* const* d_in, const int* in_sizes, int n_in,
                              void* d_out, int out_size, void* d_ws, size_t ws_size,
                              hipStream_t stream) {
    const float* x       = (const float*)d_in[0];   // [8192, 768]
    const float* pk      = (const float*)d_in[1];   // [2048, 768]
    const float* prompts = (const float*)d_in[2];   // [2048, 5, 768]

    float* out_dist = (float*)d_out;                          // [8192, 5]
    float* out_pr   = (float*)d_out + (size_t)B_ROWS * K_SEL; // [8192, 5, 5, 768]

    char* ws = (char*)d_ws;
    float*          kn       = (float*)(ws);                      //  6,291,456 B
    _Float16*       kh       = (_Float16*)(ws + 6291456);         //  3,145,728 B
    _Float16*       xh       = (_Float16*)(ws + 9437184);         // 12,582,912 B
    float*          inv_x    = (float*)(ws + 22020096);           //     32,768 B
    float*          cand_val = (float*)(ws + 22052864);           //  5,242,880 B
    unsigned short* cand_idx = (unsigned short*)(ws + 27295744);  //  2,621,440 B
    int*            final_ix = (int*)(ws + 29917184);             //    163,840 B

    // 1) keys -> kn (fp32) + kh (fp16); x -> inv_x + xh (fp16, once)
    norm_kernel<<<(P_KEYS + B_ROWS) / 4, 256, 0, stream>>>(x, pk, kn, kh, xh, inv_x);
    // 2) fp16 MFMA approx, barrier-free direct-L2 fragments
    {
        dim3 grid(NCB2, B_ROWS / RBLK);   // (32, 128)
        approx_kernel<<<grid, 256, 0, stream>>>(xh, kh, cand_val, cand_idx);
    }
    // 3) per-row wave: min-extract top-16 + exact fp32 rescore + final top-5
    select_rescore_kernel<<<B_ROWS / 4, 256, 0, stream>>>(x, kn, inv_x, cand_val, cand_idx,
                                                          out_dist, final_ix);
    // 4) gather prompts
    gather_kernel<<<B_ROWS * K_SEL, 256, 0, stream>>>(prompts, final_ix, out_pr);
}

// Round 19
// 597.795 us; speedup vs baseline: 1.3326x; 1.3326x over previous
//
#include <hip/hip_runtime.h>
#include <math.h>

#define B_ROWS 8192
#define P_KEYS 2048
#define D_DIM  768
#define L_LEN  5
#define K_SEL  5
#define EPSV   1e-8f

#define RTILE 256
#define CTILE 64
#define KB 32
#define NCB (P_KEYS / CTILE)      // 32 column blocks
#define NCAND (NCB * K_SEL)       // 160 candidates per row

// sorted ascending (v[0] best). Tie-break: lower index wins (jax top_k semantics).
__device__ inline void insert5(float (&v)[K_SEL], int (&ix)[K_SEL], float nv, int ni) {
    if (nv < v[K_SEL-1] || (nv == v[K_SEL-1] && ni < ix[K_SEL-1])) {
        v[K_SEL-1] = nv; ix[K_SEL-1] = ni;
        #pragma unroll
        for (int j = K_SEL-1; j > 0; --j) {
            bool sw = (v[j] < v[j-1]) || (v[j] == v[j-1] && ix[j] < ix[j-1]);
            if (sw) {
                float tv = v[j]; v[j] = v[j-1]; v[j-1] = tv;
                int   ti = ix[j]; ix[j] = ix[j-1]; ix[j-1] = ti;
            }
        }
    }
}

// One wave (64 lanes) per row. waves [0, P_KEYS): normalize pool_key -> kn
// (pre-normalized B: GEMM numerics must match reference's x_hat . k_hat
// per-element rounding — r10's post-scale variant flipped a near-tied top-5).
// waves [P_KEYS, ...): x -> inv_x only.  [r14-verbatim]
__global__ __launch_bounds__(256)
void norm_kernel(const float* __restrict__ x, const float* __restrict__ pk,
                 float* __restrict__ kn, float* __restrict__ inv_x) {
    int wave = (blockIdx.x * blockDim.x + threadIdx.x) >> 6;
    int lane = threadIdx.x & 63;
    bool is_key = (wave < P_KEYS);
    int row = is_key ? wave : wave - P_KEYS;
    const float* src = is_key ? (pk + (size_t)row * D_DIM) : (x + (size_t)row * D_DIM);

    const float4* s4 = (const float4*)src;
    float4 v[3];
    float s = 0.f;
    #pragma unroll
    for (int i = 0; i < 3; ++i) {
        v[i] = s4[lane + 64 * i];
        s += v[i].x * v[i].x + v[i].y * v[i].y + v[i].z * v[i].z + v[i].w * v[i].w;
    }
    #pragma unroll
    for (int off = 32; off; off >>= 1) s += __shfl_xor(s, off, 64);
    float inv = 1.0f / fmaxf(sqrtf(s), EPSV);

    if (is_key) {
        float4* d4 = (float4*)(kn + (size_t)row * D_DIM);
        #pragma unroll
        for (int i = 0; i < 3; ++i) {
            float4 w = v[i];
            w.x *= inv; w.y *= inv; w.z *= inv; w.w *= inv;
            d4[lane + 64 * i] = w;
        }
    } else {
        if (lane == 0) inv_x[row] = inv;
    }
}

// Fused fp32 GEMM (dist = 1 - x_hat . k_hat) + per-row top-5 per 64-col block.
// [r14-verbatim — best measured: 438 us, VALUBusy 58%, VGPR 56, no spill.
//  r15-r18's fp16-MFMA replacements (LDS/barrier-free/direct-L2) all sat at
//  435-460 us with MfmaUtil <=2.4% — never beat this end-to-end.]
// B wave-uniform -> s_load; 4 rows/lane (each b feeds 4 FMAs).
// grid = (NCB, B_ROWS/RTILE) = (32, 32), block = 512 (8 waves x 8 cols).
__global__ __launch_bounds__(512)
void gemm_top5_kernel(const float* __restrict__ x, const float* __restrict__ kn,
                      const float* __restrict__ inv_x,
                      float* __restrict__ cand_val, int* __restrict__ cand_idx) {
    const int cb   = blockIdx.x;
    const int rb   = blockIdx.y;
    const int row0 = rb * RTILE;
    const int tid  = threadIdx.x;
    const int lane = tid & 63;
    const int w    = __builtin_amdgcn_readfirstlane(tid >> 6);  // wave id 0..7
    const int col0w = cb * CTILE + w * 8;                        // this wave's 8 cols

    // 40 KB LDS, time-shared: phase 1 = As[256][32] (32 KB), phase 2 = merge
    __shared__ float smem[10240];
    float* As   = smem;
    float* mval = smem;                    // [256 rows][4 slots][5]
    int*   midx = (int*)smem + 256 * 4 * K_SEL;   // after 5120 floats

    // A staging: 512 threads x 4 float4 = 256 rows x 32 k
    const int sr = tid >> 3;               // 0..63
    const int sq = tid & 7;                // col-quad
    const int wq = (sq ^ (sr & 7)) * 4;    // swizzled (row&7 same for all 4 rows)
    const float* ap0 = x + (size_t)(row0 + sr) * D_DIM + sq * 4;
    float iva[4];
    #pragma unroll
    for (int m = 0; m < 4; ++m) iva[m] = inv_x[row0 + sr + 64 * m];

    const int swz = lane & 7;
    float acc[4][8] = {};

    float4 pf[4];
    #pragma unroll
    for (int m = 0; m < 4; ++m)
        pf[m] = *(const float4*)(ap0 + (size_t)m * 64 * D_DIM);

    for (int k0 = 0; k0 < D_DIM; k0 += KB) {
        __syncthreads();
        #pragma unroll
        for (int m = 0; m < 4; ++m) {
            float4 t = pf[m];
            t.x *= iva[m]; t.y *= iva[m]; t.z *= iva[m]; t.w *= iva[m];
            *(float4*)&As[(sr + 64 * m) * 32 + wq] = t;
        }
        __syncthreads();
        int knext = (k0 + KB < D_DIM) ? (k0 + KB) : 0;
        #pragma unroll
        for (int m = 0; m < 4; ++m)
            pf[m] = *(const float4*)(ap0 + (size_t)m * 64 * D_DIM + knext);

        #pragma unroll
        for (int ch = 0; ch < 4; ++ch) {   // 8-k chunks
            const int q0 = ((2 * ch) ^ swz) * 4;
            const int q1 = ((2 * ch + 1) ^ swz) * 4;
            float a[4][8];
            #pragma unroll
            for (int m = 0; m < 4; ++m) {
                float4 lo = *(const float4*)&As[(lane + 64 * m) * 32 + q0];
                float4 hi = *(const float4*)&As[(lane + 64 * m) * 32 + q1];
                a[m][0] = lo.x; a[m][1] = lo.y; a[m][2] = lo.z; a[m][3] = lo.w;
                a[m][4] = hi.x; a[m][5] = hi.y; a[m][6] = hi.z; a[m][7] = hi.w;
            }
            #pragma unroll
            for (int c = 0; c < 8; ++c) {
                // wave-uniform address -> s_load (SGPR b-operand in v_fma)
                const float* bp = kn + (size_t)(col0w + c) * D_DIM + k0 + ch * 8;
                #pragma unroll
                for (int j = 0; j < 8; ++j) {
                    float b = bp[j];
                    #pragma unroll
                    for (int m = 0; m < 4; ++m)
                        acc[m][c] += a[m][j] * b;
                }
            }
        }
    }

    // epilogue: per-lane top5 per row over this wave's 8 cols
    float tv[4][K_SEL]; int ti[4][K_SEL];
    #pragma unroll
    for (int m = 0; m < 4; ++m)
        #pragma unroll
        for (int j = 0; j < K_SEL; ++j) { tv[m][j] = 3.0e38f; ti[m][j] = 0x7fffffff; }
    #pragma unroll
    for (int m = 0; m < 4; ++m)
        #pragma unroll
        for (int c = 0; c < 8; ++c)
            insert5(tv[m], ti[m], 1.0f - acc[m][c], col0w + c);

    // pairwise wave-tree merge: 4-7 -> 0-3, 2-3 -> 0-1, 1 -> 0 (slots 0..3)
    #pragma unroll
    for (int hb = 4; hb >= 1; hb >>= 1) {
        __syncthreads();
        if (w >= hb && w < 2 * hb) {
            int s = w - hb;
            #pragma unroll
            for (int m = 0; m < 4; ++m)
                #pragma unroll
                for (int j = 0; j < K_SEL; ++j) {
                    mval[((lane + 64 * m) * 4 + s) * K_SEL + j] = tv[m][j];
                    midx[((lane + 64 * m) * 4 + s) * K_SEL + j] = ti[m][j];
                }
        }
        __syncthreads();
        if (w < hb) {
            #pragma unroll
            for (int m = 0; m < 4; ++m)
                #pragma unroll
                for (int j = 0; j < K_SEL; ++j)
                    insert5(tv[m], ti[m],
                            mval[((lane + 64 * m) * 4 + w) * K_SEL + j],
                            midx[((lane + 64 * m) * 4 + w) * K_SEL + j]);
        }
    }

    if (w == 0) {
        #pragma unroll
        for (int m = 0; m < 4; ++m) {
            int grow = row0 + lane + 64 * m;
            #pragma unroll
            for (int j = 0; j < K_SEL; ++j) {
                cand_val[((size_t)grow * NCB + cb) * K_SEL + j] = tv[m][j];
                cand_idx[((size_t)grow * NCB + cb) * K_SEL + j] = ti[m][j];
            }
        }
    }
}

// FUSED merge + gather: one block per row. LDS-stage the 160 candidates,
// thread 0 runs the EXACT r14 serial insert5 order (t = 0..159) -> identical
// selection semantics; then all 256 threads copy the 5 selected prompt slabs
// (5 x 15 KB) with coalesced float4 stores. Removes the merge dispatch and
// the final_ix global round-trip.
__global__ __launch_bounds__(256)
void select_gather_kernel(const float* __restrict__ cand_val,
                          const int* __restrict__ cand_idx,
                          const float* __restrict__ prompts,
                          float* __restrict__ out_dist, float* __restrict__ out_pr) {
    const int row = blockIdx.x;
    const int tid = threadIdx.x;
    __shared__ float sv[NCAND];
    __shared__ int   si[NCAND];
    __shared__ int   sfi[K_SEL];

    if (tid < NCAND) {
        sv[tid] = cand_val[(size_t)row * NCAND + tid];
        si[tid] = cand_idx[(size_t)row * NCAND + tid];
    }
    __syncthreads();

    if (tid == 0) {
        float fv[K_SEL]; int fi[K_SEL];
        #pragma unroll
        for (int j = 0; j < K_SEL; ++j) { fv[j] = 3.0e38f; fi[j] = 0x7fffffff; }
        for (int t = 0; t < NCAND; ++t) insert5(fv, fi, sv[t], si[t]);
        #pragma unroll
        for (int j = 0; j < K_SEL; ++j) {
            out_dist[(size_t)row * K_SEL + j] = fv[j];
            sfi[j] = fi[j];
        }
    }
    __syncthreads();

    // copy prompts[sfi[s]] (960 float4 each) to out_pr[row][s]
    #pragma unroll
    for (int s = 0; s < K_SEL; ++s) {
        const float4* src = (const float4*)(prompts + (size_t)sfi[s] * (L_LEN * D_DIM));
        float4* dst = (float4*)(out_pr + ((size_t)row * K_SEL + s) * (L_LEN * D_DIM));
        for (int i = tid; i < (L_LEN * D_DIM) / 4; i += 256) dst[i] = src[i];
    }
}

extern "C" void kernel_launch(void* const* d_in, const int* in_sizes, int n_in,
                              void* d_out, int out_size, void* d_ws, size_t ws_size,
                              hipStream_t stream) {
    const float* x       = (const float*)d_in[0];   // [8192, 768]
    const float* pk      = (const float*)d_in[1];   // [2048, 768]
    const float* prompts = (const float*)d_in[2];   // [2048, 5, 768]

    float* out_dist = (float*)d_out;                          // [8192, 5]
    float* out_pr   = (float*)d_out + (size_t)B_ROWS * K_SEL; // [8192, 5, 5, 768]

    char* ws = (char*)d_ws;
    float* kn       = (float*)(ws);                               // 6,291,456 B
    float* inv_x    = (float*)(ws + 6291456);                     //    32,768 B
    float* cand_val = (float*)(ws + 6324224);                     // 5,242,880 B
    int*   cand_idx = (int*)  (ws + 6324224 + 5242880);           // 5,242,880 B

    // 1) normalize keys -> kn; inverse norms for x
    norm_kernel<<<(P_KEYS + B_ROWS) / 4, 256, 0, stream>>>(x, pk, kn, inv_x);
    // 2) fused GEMM (SGPR-B from kn / LDS-A, 4 rows/lane) + per-colblock top5
    {
        dim3 grid(NCB, B_ROWS / RTILE);
        gemm_top5_kernel<<<grid, 512, 0, stream>>>(x, kn, inv_x, cand_val, cand_idx);
    }
    // 3) fused cross-colblock top-5 merge + prompt gather
    select_gather_kernel<<<B_ROWS, 256, 0, stream>>>(cand_val, cand_idx, prompts,
                                                     out_dist, out_pr);
}